// Round 1
// baseline (1215.606 us; speedup 1.0000x reference)
//
#include <hip/hip_runtime.h>

// Shapes fixed by the reference: B=64, N=576, C=1024.
#define B_ 64
#define N_ 576
#define C_ 1024
#define ROWS_PER_BLK 4                 // 576 % 4 == 0 -> a block never straddles batches
#define BPB (N_ / ROWS_PER_BLK)        // blocks per batch = 144

typedef float v4f __attribute__((ext_vector_type(4)));

// Fused kernel: one block = 4 rows of one batch (one wave per row).
// Phase 1: each wave loads its V row into 4 v4f regs, dots with W[0:C]
//          (budget-embedding term + bias are per-b constants -> rank-preserving,
//          dropped), publishes logit device-scope, block bumps per-batch counter.
// Spin:    thread 0 waits (acquire) until all 144 blocks of batch b published.
//          Safe: co-resident window (>=6 blocks/CU * 256 CU = 1536) >> 144 and
//          deps are only within contiguous 144-block groups under monotone dispatch.
// Phase 2: stage 576 logits -> LDS, wave computes rank of its row (tie -> lower
//          index, matching jnp.argmax first-occurrence), K = clip((int)(budget*N),1,N),
//          then stores its row FROM REGISTERS (masked) -- V is read exactly once.
__global__ __launch_bounds__(256) void k_fused(const float* __restrict__ V,
                                               const float* __restrict__ W,
                                               const float* __restrict__ token_budget,
                                               float* __restrict__ out_feat,
                                               float* __restrict__ out_mask,
                                               float* __restrict__ logits,
                                               unsigned int* __restrict__ cnt) {
    __shared__ float sl[N_];
    const int blk = blockIdx.x;
    const int b = blk / BPB;
    const int n0 = (blk - b * BPB) * ROWS_PER_BLK;
    const int t = threadIdx.x;
    const int w = t >> 6, l = t & 63;
    const int n = n0 + w;                     // this wave's row (local index in batch)
    const size_t row = (size_t)b * N_ + n;

    // ---- phase 1: row -> regs, dot(V[row], W[0:C]) ----
    const v4f* v4 = (const v4f*)(V + row * C_);
    const v4f* w4 = (const v4f*)W;            // only first C floats matter for ranking
    v4f vr[4], wr[4];
#pragma unroll
    for (int it = 0; it < 4; ++it) {
        vr[it] = v4[l + it * 64];             // full row, coalesced 1KB/instruction
        wr[it] = w4[l + it * 64];             // L2-hit broadcast
    }
    // EXACT same accumulation order as the previously-passing kernel -> bit-identical
    // logits -> identical masks.
    float acc = 0.f;
#pragma unroll
    for (int it = 0; it < 4; ++it) {
        acc += vr[it].x * wr[it].x + vr[it].y * wr[it].y +
               vr[it].z * wr[it].z + vr[it].w * wr[it].w;
    }
#pragma unroll
    for (int off = 32; off; off >>= 1) acc += __shfl_xor(acc, off, 64);

    if (l == 0)
        __hip_atomic_store(&logits[row], acc, __ATOMIC_RELAXED, __HIP_MEMORY_SCOPE_AGENT);
    __syncthreads();                          // all 4 logit stores issued
    if (t == 0)
        __hip_atomic_fetch_add(&cnt[b], 1u, __ATOMIC_RELEASE, __HIP_MEMORY_SCOPE_AGENT);

    // ---- wait for batch b complete ----
    if (t == 0) {
        while (__hip_atomic_load(&cnt[b], __ATOMIC_ACQUIRE, __HIP_MEMORY_SCOPE_AGENT)
               < (unsigned)BPB)
            __builtin_amdgcn_s_sleep(1);
    }
    __syncthreads();

    // ---- phase 2: stage batch logits (device-scope loads: cross-XCD fresh) ----
    const float* Lg = logits + (size_t)b * N_;
    sl[t]       = __hip_atomic_load(Lg + t,       __ATOMIC_RELAXED, __HIP_MEMORY_SCOPE_AGENT);
    sl[t + 256] = __hip_atomic_load(Lg + t + 256, __ATOMIC_RELAXED, __HIP_MEMORY_SCOPE_AGENT);
    if (t < 64)
        sl[t + 512] = __hip_atomic_load(Lg + t + 512, __ATOMIC_RELAXED, __HIP_MEMORY_SCOPE_AGENT);
    __syncthreads();

    int K = (int)(token_budget[b] * (float)N_);   // astype(int32) truncates toward zero
    K = K < 1 ? 1 : (K > N_ ? N_ : K);

    const float ln = acc;                     // == sl[n] bitwise
    int rank = 0;
#pragma unroll
    for (int i = 0; i < N_ / 64; ++i) {       // 9 iters
        int m = l + 64 * i;
        float lm = sl[m];
        rank += (lm > ln) || (lm == ln && m < n);
    }
#pragma unroll
    for (int off = 32; off; off >>= 1) rank += __shfl_xor(rank, off, 64);

    const float mv = (rank < K) ? 1.0f : 0.0f;    // wave-uniform after reduce
    if (l == 0) out_mask[row] = mv;

    // ---- store row from registers; nontemporal keeps the write stream out of LLC ----
    v4f* o4 = (v4f*)(out_feat + row * C_);
    if (mv != 0.0f) {
#pragma unroll
        for (int it = 0; it < 4; ++it)
            __builtin_nontemporal_store(vr[it], &o4[l + it * 64]);
    } else {
        const v4f z = {0.f, 0.f, 0.f, 0.f};
#pragma unroll
        for (int it = 0; it < 4; ++it)
            __builtin_nontemporal_store(z, &o4[l + it * 64]);
    }
}

extern "C" void kernel_launch(void* const* d_in, const int* in_sizes, int n_in,
                              void* d_out, int out_size, void* d_ws, size_t ws_size,
                              hipStream_t stream) {
    const float* V  = (const float*)d_in[0];  // [B,N,C]
    const float* tb = (const float*)d_in[1];  // [B]
    // d_in[2] (budget_embedding), W[C:2C), bias: per-row rank-preserving constants.
    const float* W  = (const float*)d_in[3];  // [1,2C]

    float* out_feat = (float*)d_out;                         // [B,N,C]
    float* out_mask = (float*)d_out + (size_t)B_ * N_ * C_;  // [B,N]

    float* ws_logits = (float*)d_ws;                         // B*N floats
    unsigned int* ws_cnt =
        (unsigned int*)((char*)d_ws + (size_t)B_ * N_ * sizeof(float));  // 64 u32

    hipMemsetAsync(ws_cnt, 0, B_ * sizeof(unsigned int), stream);  // capturable memset node
    k_fused<<<(B_ * N_) / ROWS_PER_BLK, 256, 0, stream>>>(
        V, W, tb, out_feat, out_mask, ws_logits, ws_cnt);
}

// Round 2
// 688.633 us; speedup vs baseline: 1.7652x; 1.7652x over previous
//
#include <hip/hip_runtime.h>

// Shapes fixed by the reference: B=64, N=576, C=1024.
#define B_ 64
#define N_ 576
#define C_ 1024
#define ROWS_PER_BLK 4                 // 576 % 4 == 0 -> a block never straddles batches
#define BPB (N_ / ROWS_PER_BLK)        // blocks per batch = 144
#define CNT_STRIDE 32                  // one 128B cache line per batch counter

typedef float v4f __attribute__((ext_vector_type(4)));

// Fused kernel: one block = 4 rows of one batch (one wave per row).
// Phase 1: each wave loads its V row, dots with W[0:C] (budget-embedding term +
//          bias are per-b constants -> rank-preserving, dropped), publishes its
//          logit with a relaxed agent store, block bumps per-batch counter
//          (release).
// Wait:    thread 0 polls the counter with RELAXED agent loads + s_sleep.
//          (Round-1 lesson: an ACQUIRE in the poll loop emits a cache
//          invalidate per probe -> device-wide invalidate storm, 225 GB/s.
//          One acquire AFTER the loop pairs with the releasing fetch_add.)
//          Liveness: resident window (8 blk/CU * 256 CU = 2048) >> 144-block
//          batch span; oldest resident batch always completes -> progress.
// Phase 2: stage batch logits -> LDS, rank this block's 4 rows (tie -> lower
//          index, matching jnp.argmax first-occurrence), K=clip((int)(budget*N),1,N),
//          re-load the 4 rows (L1/L2-hot on this CU) and store masked.
__global__ __launch_bounds__(256) void k_fused(const float* __restrict__ V,
                                               const float* __restrict__ W,
                                               const float* __restrict__ token_budget,
                                               float* __restrict__ out_feat,
                                               float* __restrict__ out_mask,
                                               float* __restrict__ logits,
                                               unsigned int* __restrict__ cnt) {
    __shared__ float sl[N_];
    const int blk = blockIdx.x;
    const int b = blk / BPB;
    const int n0 = (blk - b * BPB) * ROWS_PER_BLK;
    const int t = threadIdx.x;
    const int w = t >> 6, l = t & 63;
    const int n = n0 + w;                     // this wave's row (local index in batch)
    const size_t row = (size_t)b * N_ + n;

    // ---- phase 1: dot(V[row], W[0:C]) ----
    const v4f* v4 = (const v4f*)(V + row * C_);
    const v4f* w4 = (const v4f*)W;            // only first C floats matter for ranking
    // EXACT same accumulation order as the passing kernels -> bit-identical logits.
    float acc = 0.f;
#pragma unroll
    for (int it = 0; it < 4; ++it) {
        v4f v = v4[l + it * 64];              // coalesced 1KB/instruction, L2-cached
        v4f wv = w4[l + it * 64];
        acc += v.x * wv.x + v.y * wv.y + v.z * wv.z + v.w * wv.w;
    }
#pragma unroll
    for (int off = 32; off; off >>= 1) acc += __shfl_xor(acc, off, 64);

    if (l == 0)
        __hip_atomic_store(&logits[row], acc, __ATOMIC_RELAXED, __HIP_MEMORY_SCOPE_AGENT);
    __syncthreads();                          // all 4 logit stores issued
    if (t == 0)
        __hip_atomic_fetch_add(&cnt[b * CNT_STRIDE], 1u,
                               __ATOMIC_RELEASE, __HIP_MEMORY_SCOPE_AGENT);

    // ---- wait for batch b complete: relaxed polls, ONE acquire on exit ----
    if (t == 0) {
        while (__hip_atomic_load(&cnt[b * CNT_STRIDE],
                                 __ATOMIC_RELAXED, __HIP_MEMORY_SCOPE_AGENT)
               < (unsigned)BPB)
            __builtin_amdgcn_s_sleep(32);     // ~0.85us per probe, no invalidates
        (void)__hip_atomic_load(&cnt[b * CNT_STRIDE],
                                __ATOMIC_ACQUIRE, __HIP_MEMORY_SCOPE_AGENT);
    }
    __syncthreads();

    // ---- phase 2: stage batch logits (agent-scope loads: cross-XCD fresh) ----
    const float* Lg = logits + (size_t)b * N_;
    sl[t]       = __hip_atomic_load(Lg + t,       __ATOMIC_RELAXED, __HIP_MEMORY_SCOPE_AGENT);
    sl[t + 256] = __hip_atomic_load(Lg + t + 256, __ATOMIC_RELAXED, __HIP_MEMORY_SCOPE_AGENT);
    if (t < 64)
        sl[t + 512] = __hip_atomic_load(Lg + t + 512, __ATOMIC_RELAXED, __HIP_MEMORY_SCOPE_AGENT);
    __syncthreads();

    int K = (int)(token_budget[b] * (float)N_);   // astype(int32) truncates toward zero
    K = K < 1 ? 1 : (K > N_ ? N_ : K);

    const float ln = acc;                     // == sl[n] bitwise
    int rank = 0;
#pragma unroll
    for (int i = 0; i < N_ / 64; ++i) {       // 9 iters
        int m = l + 64 * i;
        float lm = sl[m];
        rank += (lm > ln) || (lm == ln && m < n);
    }
#pragma unroll
    for (int off = 32; off; off >>= 1) rank += __shfl_xor(rank, off, 64);

    const float mv = (rank < K) ? 1.0f : 0.0f;    // wave-uniform after reduce
    if (l == 0) out_mask[row] = mv;

    // ---- store row; reload is L1/L2-hot (same CU read it in phase 1) ----
    v4f* o4 = (v4f*)(out_feat + row * C_);
    if (mv != 0.0f) {
#pragma unroll
        for (int it = 0; it < 4; ++it)
            __builtin_nontemporal_store(v4[l + it * 64], &o4[l + it * 64]);
    } else {
        const v4f z = {0.f, 0.f, 0.f, 0.f};
#pragma unroll
        for (int it = 0; it < 4; ++it)
            __builtin_nontemporal_store(z, &o4[l + it * 64]);
    }
}

extern "C" void kernel_launch(void* const* d_in, const int* in_sizes, int n_in,
                              void* d_out, int out_size, void* d_ws, size_t ws_size,
                              hipStream_t stream) {
    const float* V  = (const float*)d_in[0];  // [B,N,C]
    const float* tb = (const float*)d_in[1];  // [B]
    // d_in[2] (budget_embedding), W[C:2C), bias: per-row rank-preserving constants.
    const float* W  = (const float*)d_in[3];  // [1,2C]

    float* out_feat = (float*)d_out;                         // [B,N,C]
    float* out_mask = (float*)d_out + (size_t)B_ * N_ * C_;  // [B,N]

    float* ws_logits = (float*)d_ws;                         // B*N floats
    unsigned int* ws_cnt =
        (unsigned int*)((char*)d_ws + (size_t)B_ * N_ * sizeof(float));  // 64 lines

    hipMemsetAsync(ws_cnt, 0, B_ * CNT_STRIDE * sizeof(unsigned int), stream);
    k_fused<<<(B_ * N_) / ROWS_PER_BLK, 256, 0, stream>>>(
        V, W, tb, out_feat, out_mask, ws_logits, ws_cnt);
}

// Round 3
// 346.364 us; speedup vs baseline: 3.5096x; 1.9882x over previous
//
#include <hip/hip_runtime.h>

// Shapes fixed by the reference: B=64, N=576, C=1024.
#define B_ 64
#define N_ 576
#define C_ 1024
#define ROWS_PER_BLK 4                 // 576 % 4 == 0 -> a block never straddles batches
#define BPB (N_ / ROWS_PER_BLK)        // blocks per batch = 144
#define CNT_STRIDE 32                  // one 128B cache line per batch counter

typedef float v4f __attribute__((ext_vector_type(4)));

// Fused kernel: one block = 4 rows of one batch (one wave per row).
//
// Sync protocol (ZERO cache-maintenance ops -- this is the point):
//  * all cross-block data (logits, counters) moves via RELAXED agent-scope
//    atomics, which bypass L1/L2 and are served at the coherent LLC.
//  * "logit store before counter bump" ordering comes from __syncthreads(),
//    which emits s_waitcnt vmcnt(0) (store acked at coherence point) and is a
//    compiler fence.
//  * Round-1 lesson: acquire-per-poll = invalidate storm (225 GB/s).
//    Round-2 lesson: even ONE release(+wbl2) / acquire(+inv) per block is
//    9216 L2 writeback/invalidate walks -> 475 GB/s. Remove them entirely.
//
// Liveness: resident window (8 blk/CU * 256 CU = 2048) >> 144-block batch
// span; deps only within contiguous 144-block groups under monotone dispatch.
__global__ __launch_bounds__(256) void k_fused(const float* __restrict__ V,
                                               const float* __restrict__ W,
                                               const float* __restrict__ token_budget,
                                               float* __restrict__ out_feat,
                                               float* __restrict__ out_mask,
                                               float* __restrict__ logits,
                                               unsigned int* __restrict__ cnt) {
    __shared__ float sl[N_];
    const int blk = blockIdx.x;
    const int b = blk / BPB;
    const int n0 = (blk - b * BPB) * ROWS_PER_BLK;
    const int t = threadIdx.x;
    const int w = t >> 6, l = t & 63;
    const int n = n0 + w;                     // this wave's row (local index in batch)
    const size_t row = (size_t)b * N_ + n;

    // ---- phase 1: dot(V[row], W[0:C]) ----
    // (budget-embedding term + bias are per-b constants -> rank-preserving, dropped)
    const v4f* v4 = (const v4f*)(V + row * C_);
    const v4f* w4 = (const v4f*)W;            // only first C floats matter for ranking
    // EXACT same accumulation order as the passing kernels -> bit-identical logits.
    float acc = 0.f;
#pragma unroll
    for (int it = 0; it < 4; ++it) {
        v4f v = v4[l + it * 64];              // coalesced 1KB/instruction, L2-cached
        v4f wv = w4[l + it * 64];
        acc += v.x * wv.x + v.y * wv.y + v.z * wv.z + v.w * wv.w;
    }
#pragma unroll
    for (int off = 32; off; off >>= 1) acc += __shfl_xor(acc, off, 64);

    if (l == 0)
        __hip_atomic_store(&logits[row], acc, __ATOMIC_RELAXED, __HIP_MEMORY_SCOPE_AGENT);
    __syncthreads();                          // s_waitcnt vmcnt(0): logit stores acked
    if (t == 0)
        __hip_atomic_fetch_add(&cnt[b * CNT_STRIDE], 1u,
                               __ATOMIC_RELAXED, __HIP_MEMORY_SCOPE_AGENT);

    // ---- wait for batch b complete: relaxed polls only ----
    if (t == 0) {
        while (__hip_atomic_load(&cnt[b * CNT_STRIDE],
                                 __ATOMIC_RELAXED, __HIP_MEMORY_SCOPE_AGENT)
               < (unsigned)BPB)
            __builtin_amdgcn_s_sleep(32);     // ~0.85us per probe
    }
    __syncthreads();

    // ---- phase 2: stage batch logits (uncached atomic loads read the LLC) ----
    const float* Lg = logits + (size_t)b * N_;
    sl[t]       = __hip_atomic_load(Lg + t,       __ATOMIC_RELAXED, __HIP_MEMORY_SCOPE_AGENT);
    sl[t + 256] = __hip_atomic_load(Lg + t + 256, __ATOMIC_RELAXED, __HIP_MEMORY_SCOPE_AGENT);
    if (t < 64)
        sl[t + 512] = __hip_atomic_load(Lg + t + 512, __ATOMIC_RELAXED, __HIP_MEMORY_SCOPE_AGENT);
    __syncthreads();

    int K = (int)(token_budget[b] * (float)N_);   // astype(int32) truncates toward zero
    K = K < 1 ? 1 : (K > N_ ? N_ : K);

    const float ln = acc;                     // == sl[n] bitwise
    int rank = 0;
#pragma unroll
    for (int i = 0; i < N_ / 64; ++i) {       // 9 iters
        int m = l + 64 * i;
        float lm = sl[m];
        rank += (lm > ln) || (lm == ln && m < n);
    }
#pragma unroll
    for (int off = 32; off; off >>= 1) rank += __shfl_xor(rank, off, 64);

    const float mv = (rank < K) ? 1.0f : 0.0f;    // wave-uniform after reduce
    if (l == 0) out_mask[row] = mv;

    // ---- store row; reload is L1/L2-hot (same CU read it in phase 1, and no
    //      invalidates ran in between) ----
    v4f* o4 = (v4f*)(out_feat + row * C_);
    if (mv != 0.0f) {
#pragma unroll
        for (int it = 0; it < 4; ++it)
            __builtin_nontemporal_store(v4[l + it * 64], &o4[l + it * 64]);
    } else {
        const v4f z = {0.f, 0.f, 0.f, 0.f};
#pragma unroll
        for (int it = 0; it < 4; ++it)
            __builtin_nontemporal_store(z, &o4[l + it * 64]);
    }
}

extern "C" void kernel_launch(void* const* d_in, const int* in_sizes, int n_in,
                              void* d_out, int out_size, void* d_ws, size_t ws_size,
                              hipStream_t stream) {
    const float* V  = (const float*)d_in[0];  // [B,N,C]
    const float* tb = (const float*)d_in[1];  // [B]
    // d_in[2] (budget_embedding), W[C:2C), bias: per-row rank-preserving constants.
    const float* W  = (const float*)d_in[3];  // [1,2C]

    float* out_feat = (float*)d_out;                         // [B,N,C]
    float* out_mask = (float*)d_out + (size_t)B_ * N_ * C_;  // [B,N]

    float* ws_logits = (float*)d_ws;                         // B*N floats
    unsigned int* ws_cnt =
        (unsigned int*)((char*)d_ws + (size_t)B_ * N_ * sizeof(float));  // 64 lines

    hipMemsetAsync(ws_cnt, 0, B_ * CNT_STRIDE * sizeof(unsigned int), stream);
    k_fused<<<(B_ * N_) / ROWS_PER_BLK, 256, 0, stream>>>(
        V, W, tb, out_feat, out_mask, ws_logits, ws_cnt);
}

// Round 4
// 312.987 us; speedup vs baseline: 3.8839x; 1.1066x over previous
//
#include <hip/hip_runtime.h>

// Shapes fixed by the reference: B=64, N=576, C=1024.
#define B_ 64
#define N_ 576
#define C_ 1024
#define RPB 4                        // rows per block-iteration (one wave per row)
#define GPB (N_ / RPB)               // row-groups per batch = 144
#define NGROUPS (B_ * N_ / RPB)      // 2304 row-groups total
#define MAX_GRID 2048                // 8 blocks/CU * 256 CU upper bound

typedef float v4f __attribute__((ext_vector_type(4)));

// Single-launch, single GRID-WIDE barrier (round-3 lesson: 64 per-batch
// barriers serialize phase 2 into 144-block bursts -> 2.25 waves/CU doing the
// write stream -> 1.4 TB/s. One grid barrier restores full parallelism to
// BOTH phases, like the two-kernel split, minus the launch and with V hot in
// LLC for the phase-2 re-read.)
//
// Sync protocol (zero cache-maintenance ops, proven in rounds 2-3):
//  * logits + barrier counter move via RELAXED agent-scope atomics (bypass
//    L1/L2, served at the coherent LLC).
//  * "logit stores before counter bump": __syncthreads() emits
//    s_waitcnt vmcnt(0) (stores acked at the coherence point).
//  * poll is a relaxed load + s_sleep(8); no acquire anywhere.
// Co-residency for the barrier: grid sized from the occupancy API (cached on
// host), clamped to MAX_GRID; grid-stride loops handle any grid size.
__global__ __launch_bounds__(256) void k_fused2(const float* __restrict__ V,
                                                const float* __restrict__ W,
                                                const float* __restrict__ token_budget,
                                                float* __restrict__ out_feat,
                                                float* __restrict__ out_mask,
                                                float* __restrict__ logits,
                                                unsigned int* __restrict__ bar,
                                                int nblk) {
    __shared__ float sl[N_];
    const int t = threadIdx.x;
    const int w = t >> 6, l = t & 63;
    const v4f* w4 = (const v4f*)W;        // only first C floats matter for ranking
                                          // (budget-embedding term + bias are per-b
                                          // constants -> rank-preserving, dropped)

    // ---- phase 1: grid-stride over row-groups, one wave per row ----
    for (int g = blockIdx.x; g < NGROUPS; g += nblk) {
        const size_t row = (size_t)g * RPB + w;
        const v4f* v4 = (const v4f*)(V + row * C_);
        // EXACT same accumulation order as all passing versions -> bit-identical logits.
        float acc = 0.f;
#pragma unroll
        for (int it = 0; it < 4; ++it) {
            v4f v = v4[l + it * 64];      // coalesced 1KB/instruction
            v4f wv = w4[l + it * 64];     // L1-hot broadcast
            acc += v.x * wv.x + v.y * wv.y + v.z * wv.z + v.w * wv.w;
        }
#pragma unroll
        for (int off = 32; off; off >>= 1) acc += __shfl_xor(acc, off, 64);
        if (l == 0)
            __hip_atomic_store(&logits[row], acc,
                               __ATOMIC_RELAXED, __HIP_MEMORY_SCOPE_AGENT);
    }
    __syncthreads();                      // vmcnt(0): this block's logit stores acked

    // ---- grid barrier: relaxed arrive + relaxed poll ----
    if (t == 0) {
        __hip_atomic_fetch_add(bar, 1u, __ATOMIC_RELAXED, __HIP_MEMORY_SCOPE_AGENT);
        while (__hip_atomic_load(bar, __ATOMIC_RELAXED, __HIP_MEMORY_SCOPE_AGENT)
               < (unsigned)nblk)
            __builtin_amdgcn_s_sleep(8);  // ~0.2us per probe, tiny LLC traffic
    }
    __syncthreads();

    // ---- phase 2: same groups (locality), full grid parallelism ----
    for (int g = blockIdx.x; g < NGROUPS; g += nblk) {
        const int b = g / GPB;
        const int n = (g - b * GPB) * RPB + w;    // this wave's row within batch
        const size_t row = (size_t)b * N_ + n;

        __syncthreads();                  // sl reuse guard across iterations
        const float* Lg = logits + (size_t)b * N_;
        sl[t]       = __hip_atomic_load(Lg + t,       __ATOMIC_RELAXED, __HIP_MEMORY_SCOPE_AGENT);
        sl[t + 256] = __hip_atomic_load(Lg + t + 256, __ATOMIC_RELAXED, __HIP_MEMORY_SCOPE_AGENT);
        if (t < 64)
            sl[t + 512] = __hip_atomic_load(Lg + t + 512, __ATOMIC_RELAXED, __HIP_MEMORY_SCOPE_AGENT);
        __syncthreads();

        int K = (int)(token_budget[b] * (float)N_);  // astype(int32) truncates toward zero
        K = K < 1 ? 1 : (K > N_ ? N_ : K);

        const float ln = sl[n];
        int rank = 0;
#pragma unroll
        for (int i = 0; i < N_ / 64; ++i) {          // 9 iters; tie -> lower index
            int m = l + 64 * i;                      // (jnp.argmax first-occurrence)
            float lm = sl[m];
            rank += (lm > ln) || (lm == ln && m < n);
        }
#pragma unroll
        for (int off = 32; off; off >>= 1) rank += __shfl_xor(rank, off, 64);

        const float mv = (rank < K) ? 1.0f : 0.0f;   // wave-uniform after reduce
        if (l == 0) out_mask[row] = mv;

        // row copy/zero; V re-read is LLC-hot (phase 1 just streamed it)
        const v4f* v4 = (const v4f*)(V + row * C_);
        v4f* o4 = (v4f*)(out_feat + row * C_);
        if (mv != 0.0f) {
#pragma unroll
            for (int it = 0; it < 4; ++it)
                __builtin_nontemporal_store(v4[l + it * 64], &o4[l + it * 64]);
        } else {
            const v4f z = {0.f, 0.f, 0.f, 0.f};
#pragma unroll
            for (int it = 0; it < 4; ++it)
                __builtin_nontemporal_store(z, &o4[l + it * 64]);
        }
    }
}

extern "C" void kernel_launch(void* const* d_in, const int* in_sizes, int n_in,
                              void* d_out, int out_size, void* d_ws, size_t ws_size,
                              hipStream_t stream) {
    const float* V  = (const float*)d_in[0];  // [B,N,C]
    const float* tb = (const float*)d_in[1];  // [B]
    // d_in[2] (budget_embedding), W[C:2C), bias: per-row rank-preserving constants.
    const float* W  = (const float*)d_in[3];  // [1,2C]

    float* out_feat = (float*)d_out;                         // [B,N,C]
    float* out_mask = (float*)d_out + (size_t)B_ * N_ * C_;  // [B,N]

    float* ws_logits = (float*)d_ws;                         // B*N floats
    unsigned int* ws_bar =
        (unsigned int*)((char*)d_ws + (size_t)B_ * N_ * sizeof(float));

    // Co-residency: size the grid from measured occupancy (host query, cached;
    // runs at capture time -- no banned calls).
    static int nblk_cached = 0;
    if (nblk_cached == 0) {
        int nb = 0;
        hipOccupancyMaxActiveBlocksPerMultiprocessor(&nb, k_fused2, 256, 0);
        if (nb < 1) nb = 1;
        long g = (long)nb * 256;          // 256 CUs on MI355X
        if (g > MAX_GRID) g = MAX_GRID;
        if (g > NGROUPS) g = NGROUPS;
        nblk_cached = (int)g;
    }
    const int nblk = nblk_cached;

    hipMemsetAsync(ws_bar, 0, sizeof(unsigned int), stream);  // capturable node
    k_fused2<<<nblk, 256, 0, stream>>>(V, W, tb, out_feat, out_mask,
                                       ws_logits, ws_bar, nblk);
}

// Round 5
// 293.172 us; speedup vs baseline: 4.1464x; 1.0676x over previous
//
#include <hip/hip_runtime.h>

// Shapes fixed by the reference: B=64, N=576, C=1024.
#define B_ 64
#define N_ 576
#define C_ 1024
#define SLICES 4                      // blocks per batch; each owns 144 output rows
#define SLICE_ROWS (N_ / SLICES)      // 144
#define TPB 1024                      // 16 waves -> 4 waves/SIMD, 1 block/CU at grid=256
#define WAVES (TPB / 64)              // 16
#define ROWS_A (N_ / WAVES)           // 36 logit rows per wave (phase A)
#define ROWS_B (SLICE_ROWS / WAVES)   // 9 output rows per wave (phase B)

typedef float v4f __attribute__((ext_vector_type(4)));

// One launch, ZERO cross-block sync (rounds 1-4 lesson: every cross-block
// protocol -- fenced or relaxed, per-batch or grid-wide -- cost 100+ us).
// Instead: redundant logit compute. A batch's V slab is 2.25 MB; each of its
// 4 slice-blocks recomputes ALL 576 logits into LDS (bit-identical expression
// -> bit-identical logits -> consistent masks, no communication), local
// __syncthreads, then ranks + copies only its own 144-row slice.
// Traffic: HBM R=151 MB unique (4x redundancy served by LLC/MALL -- the 4
// slice-blocks of a batch are dispatched back-to-back), HBM W=149 MB NT.
// Redundant FLOPs: 4x logits = 0.3 GFLOP total -- noise vs 157 TF.
__global__ __launch_bounds__(TPB) void k_onepass(const float* __restrict__ V,
                                                 const float* __restrict__ W,
                                                 const float* __restrict__ token_budget,
                                                 float* __restrict__ out_feat,
                                                 float* __restrict__ out_mask) {
    __shared__ float sl[N_];
    const int blk = blockIdx.x;
    const int b = blk >> 2;           // batch
    const int r = blk & 3;            // slice within batch
    const int t = threadIdx.x;
    const int w = t >> 6, l = t & 63;

    // Hoist the W fragment: identical for every row (36-row amortization).
    // Only first C floats matter for ranking (budget-embedding term + bias are
    // per-b constants -> rank-preserving, dropped; validated rounds 0-4).
    const v4f* w4 = (const v4f*)W;
    v4f wr[4];
#pragma unroll
    for (int it = 0; it < 4; ++it) wr[it] = w4[l + it * 64];

    const float* Vb = V + (size_t)b * N_ * C_;

    // ---- phase A: all 576 logits of batch b (one wave per row, 36 rows/wave).
    // EXACT accumulation order of every passing version -> bit-identical logits.
    for (int j = 0; j < ROWS_A; ++j) {
        const int n = w * ROWS_A + j;
        const v4f* v4 = (const v4f*)(Vb + (size_t)n * C_);
        float acc = 0.f;
#pragma unroll
        for (int it = 0; it < 4; ++it) {
            v4f v = v4[l + it * 64];          // coalesced 1KB/instruction
            acc += v.x * wr[it].x + v.y * wr[it].y + v.z * wr[it].z + v.w * wr[it].w;
        }
#pragma unroll
        for (int off = 32; off; off >>= 1) acc += __shfl_xor(acc, off, 64);
        if (l == 0) sl[n] = acc;
    }
    __syncthreads();                          // block-local: the only barrier

    int K = (int)(token_budget[b] * (float)N_);   // astype(int32) truncates toward zero
    K = K < 1 ? 1 : (K > N_ ? N_ : N_), K = K > N_ ? N_ : K;
    K = (int)(token_budget[b] * (float)N_);
    K = K < 1 ? 1 : (K > N_ ? N_ : K);

    // ---- phase B: rank + copy this block's 144-row slice (9 rows/wave) ----
    for (int j = 0; j < ROWS_B; ++j) {
        const int n = r * SLICE_ROWS + w * ROWS_B + j;   // batch-local row
        const float ln = sl[n];
        int rank = 0;
#pragma unroll
        for (int i = 0; i < N_ / 64; ++i) {   // 9 iters; tie -> lower index
            int m = l + 64 * i;               // (jnp.argmax first-occurrence)
            float lm = sl[m];
            rank += (lm > ln) || (lm == ln && m < n);
        }
#pragma unroll
        for (int off = 32; off; off >>= 1) rank += __shfl_xor(rank, off, 64);

        const size_t row = (size_t)b * N_ + n;
        const float mv = (rank < K) ? 1.0f : 0.0f;   // wave-uniform after reduce
        if (l == 0) out_mask[row] = mv;

        // copy/zero; V re-read is LLC-hot (phase A just pulled the slab in).
        // NT stores bypass LLC -> V stays resident for the other slice-blocks.
        const v4f* v4 = (const v4f*)(V + row * C_);
        v4f* o4 = (v4f*)(out_feat + row * C_);
        if (mv != 0.0f) {
#pragma unroll
            for (int it = 0; it < 4; ++it)
                __builtin_nontemporal_store(v4[l + it * 64], &o4[l + it * 64]);
        } else {
            const v4f z = {0.f, 0.f, 0.f, 0.f};
#pragma unroll
            for (int it = 0; it < 4; ++it)
                __builtin_nontemporal_store(z, &o4[l + it * 64]);
        }
    }
}

extern "C" void kernel_launch(void* const* d_in, const int* in_sizes, int n_in,
                              void* d_out, int out_size, void* d_ws, size_t ws_size,
                              hipStream_t stream) {
    const float* V  = (const float*)d_in[0];  // [B,N,C]
    const float* tb = (const float*)d_in[1];  // [B]
    // d_in[2] (budget_embedding), W[C:2C), bias: per-row rank-preserving constants.
    const float* W  = (const float*)d_in[3];  // [1,2C]

    float* out_feat = (float*)d_out;                         // [B,N,C]
    float* out_mask = (float*)d_out + (size_t)B_ * N_ * C_;  // [B,N]

    // No workspace, no memset, no sync objects: 256 blocks (1 per CU), 16 waves.
    k_onepass<<<B_ * SLICES, TPB, 0, stream>>>(V, W, tb, out_feat, out_mask);
}

// Round 6
// 275.691 us; speedup vs baseline: 4.4093x; 1.0634x over previous
//
#include <hip/hip_runtime.h>

// Shapes fixed by the reference: B=64, N=576, C=1024.
#define B_ 64
#define N_ 576
#define C_ 1024
#define SLICES 4                      // blocks per batch; each owns 144 output rows
#define SLICE_ROWS (N_ / SLICES)      // 144
#define TPB 1024                      // 16 waves -> 1 block/CU at grid=256
#define WAVES (TPB / 64)              // 16
#define ROWS_A (N_ / WAVES)           // 36 logit rows per wave (phase A)
#define ROWS_B (SLICE_ROWS / WAVES)   // 9 output rows per wave (phase B)
#define NXCD 8

typedef float v4f __attribute__((ext_vector_type(4)));

// One launch, ZERO cross-block sync (rounds 1-4: every cross-block protocol
// cost 100+ us). Redundant logit compute: each of a batch's 4 slice-blocks
// recomputes all 576 logits into LDS (bit-identical expression -> consistent
// masks, no communication), then ranks + copies its own 144-row slice.
//
// Round-5 lesson: with naive blockIdx, the 4 slice-blocks of a batch land on
// 4 DIFFERENT XCDs (round-robin %8) -> each XCD's private L2 refetches the
// 2.25MB slab -> FETCH=324MB (2.15x V). Fix: swizzle so a batch's 4 blocks
// share one XCD (same blockIdx%8). They walk the slab in lockstep -> MSHR
// merge: 1 fill + 3 hits per line. Per-XCD unique fill drops 72->18MB.
// If the %8 mapping assumption is wrong this is a harmless permutation.
__global__ __launch_bounds__(TPB) void k_onepass(const float* __restrict__ V,
                                                 const float* __restrict__ W,
                                                 const float* __restrict__ token_budget,
                                                 float* __restrict__ out_feat,
                                                 float* __restrict__ out_mask) {
    __shared__ float sl[N_];
    const int p = blockIdx.x;
    const int xcd = p & (NXCD - 1);           // assumed XCD under round-robin dispatch
    const int k = p >> 3;                     // 0..31 within XCD
    const int b = xcd * (B_ / NXCD) + (k & 7);    // batch: 8 per XCD
    const int r = k >> 3;                     // slice 0..3 (same xcd for all 4)
    const int t = threadIdx.x;
    const int w = t >> 6, l = t & 63;

    // Hoist the W fragment: identical for every row. Only first C floats
    // matter for ranking (budget-embedding term + bias are per-b constants ->
    // rank-preserving, dropped; validated rounds 0-5).
    const v4f* w4 = (const v4f*)W;
    v4f wr[4];
#pragma unroll
    for (int it = 0; it < 4; ++it) wr[it] = w4[l + it * 64];

    const float* Vb = V + (size_t)b * N_ * C_;

    // ---- phase A: all 576 logits of batch b (one wave per row, 36 rows/wave).
    // EXACT accumulation order of every passing version -> bit-identical logits.
#pragma unroll 4
    for (int j = 0; j < ROWS_A; ++j) {
        const int n = w * ROWS_A + j;
        const v4f* v4 = (const v4f*)(Vb + (size_t)n * C_);
        float acc = 0.f;
#pragma unroll
        for (int it = 0; it < 4; ++it) {
            v4f v = v4[l + it * 64];          // coalesced 1KB/instruction
            acc += v.x * wr[it].x + v.y * wr[it].y + v.z * wr[it].z + v.w * wr[it].w;
        }
#pragma unroll
        for (int off = 32; off; off >>= 1) acc += __shfl_xor(acc, off, 64);
        if (l == 0) sl[n] = acc;
    }
    __syncthreads();                          // block-local: the only barrier

    int K = (int)(token_budget[b] * (float)N_);   // astype(int32) truncates toward zero
    K = K < 1 ? 1 : (K > N_ ? N_ : K);

    // ---- phase B: rank + copy this block's 144-row slice (9 rows/wave) ----
    for (int j = 0; j < ROWS_B; ++j) {
        const int n = r * SLICE_ROWS + w * ROWS_B + j;   // batch-local row
        const float ln = sl[n];
        int rank = 0;
#pragma unroll
        for (int i = 0; i < N_ / 64; ++i) {   // 9 iters; tie -> lower index
            int m = l + 64 * i;               // (jnp.argmax first-occurrence)
            float lm = sl[m];
            rank += (lm > ln) || (lm == ln && m < n);
        }
#pragma unroll
        for (int off = 32; off; off >>= 1) rank += __shfl_xor(rank, off, 64);

        const size_t row = (size_t)b * N_ + n;
        const float mv = (rank < K) ? 1.0f : 0.0f;   // wave-uniform after reduce
        if (l == 0) out_mask[row] = mv;

        // copy/zero; kept-row re-read is L2/LLC-hot (phase A streamed the slab).
        // NT stores bypass LLC -> V stays resident for the sibling slices.
        const v4f* v4 = (const v4f*)(V + row * C_);
        v4f* o4 = (v4f*)(out_feat + row * C_);
        if (mv != 0.0f) {
#pragma unroll
            for (int it = 0; it < 4; ++it)
                __builtin_nontemporal_store(v4[l + it * 64], &o4[l + it * 64]);
        } else {
            const v4f z = {0.f, 0.f, 0.f, 0.f};
#pragma unroll
            for (int it = 0; it < 4; ++it)
                __builtin_nontemporal_store(z, &o4[l + it * 64]);
        }
    }
}

extern "C" void kernel_launch(void* const* d_in, const int* in_sizes, int n_in,
                              void* d_out, int out_size, void* d_ws, size_t ws_size,
                              hipStream_t stream) {
    const float* V  = (const float*)d_in[0];  // [B,N,C]
    const float* tb = (const float*)d_in[1];  // [B]
    // d_in[2] (budget_embedding), W[C:2C), bias: per-row rank-preserving constants.
    const float* W  = (const float*)d_in[3];  // [1,2C]

    float* out_feat = (float*)d_out;                         // [B,N,C]
    float* out_mask = (float*)d_out + (size_t)B_ * N_ * C_;  // [B,N]

    // No workspace, no memset, no sync objects: 256 blocks (1 per CU), 16 waves.
    k_onepass<<<B_ * SLICES, TPB, 0, stream>>>(V, W, tb, out_feat, out_mask);
}